// Round 1
// baseline (686.648 us; speedup 1.0000x reference)
//
#include <hip/hip_runtime.h>
#include <math.h>

typedef __attribute__((ext_vector_type(8))) short short8;
typedef __attribute__((ext_vector_type(4))) float float4v;

#define AST 136   // activation row stride (bf16 elems) for 128-wide buffers
#define CST 424   // cat row stride (bf16 elems), 416 padded, 848B = 16B-aligned

__device__ __forceinline__ unsigned short f2bf(float f) {
    union { float f; unsigned u; } v; v.f = f;
    return (unsigned short)((v.u + 0x7fffu + ((v.u >> 16) & 1u)) >> 16);
}
__device__ __forceinline__ float bf2f(unsigned v) {
    union { unsigned u; float f; } x; x.u = v << 16; return x.f;
}

// ---------------------------------------------------------------------------
// 2x2-tile MFMA layer: block's 64-row A-tile in shared LDS (stride astr); this
// wave computes m-tiles mt0,mt0+1 x n-tiles nt0,nt0+1 (32x32 output).
// Wave grid 2(m) x 4(n) over 8 waves: A-read redundancy 4 (same as 4-wave
// 4x2 layout) but 2x the waves/SIMD for latency hiding.
// ---------------------------------------------------------------------------
template<int KP>
__device__ __forceinline__ void layer22(const unsigned short* X, int astr,
                                        const unsigned short* __restrict__ WT,
                                        const float* __restrict__ bias,
                                        int lane, int mt0, int nt0, float4v acc[2][2])
{
    const int col0 = lane & 15, q = lane >> 4;
#pragma unroll
    for (int t = 0; t < 2; ++t) {
        float b = bias[(nt0 + t) * 16 + col0];
#pragma unroll
        for (int mt = 0; mt < 2; ++mt) acc[mt][t] = (float4v){b, b, b, b};
    }
#pragma unroll
    for (int ks = 0; ks < KP; ks += 32) {
        const int k0 = ks + q * 8;
        short8 B[2];
#pragma unroll
        for (int t = 0; t < 2; ++t)
            B[t] = *(const short8*)(WT + (size_t)((nt0 + t) * 16 + col0) * KP + k0);
#pragma unroll
        for (int mt = 0; mt < 2; ++mt) {
            short8 A = *(const short8*)(X + ((mt0 + mt) * 16 + col0) * astr + k0);
#pragma unroll
            for (int t = 0; t < 2; ++t)
                acc[mt][t] = __builtin_amdgcn_mfma_f32_16x16x32_bf16(A, B[t], acc[mt][t], 0, 0, 0);
        }
    }
}

// C/D: col = (nt0+t)*16+col0, row = (mt0+mt)*16 + q*4 + r
__device__ __forceinline__ void store22(float4v acc[2][2], unsigned short* Y,
                                        int lane, int mt0, int nt0, bool relu)
{
    const int col0 = lane & 15, q = lane >> 4;
#pragma unroll
    for (int mt = 0; mt < 2; ++mt)
#pragma unroll
        for (int t = 0; t < 2; ++t)
#pragma unroll
            for (int r = 0; r < 4; ++r) {
                float v = acc[mt][t][r];
                if (relu) v = fmaxf(v, 0.0f);
                Y[((mt0 + mt) * 16 + q * 4 + r) * AST + (nt0 + t) * 16 + col0] = f2bf(v);
            }
}

// ---------------------------------------------------------------------------
// weight prep: fp32 [K][128] -> bf16 transposed [128][KP] (zero k-padding)
// ---------------------------------------------------------------------------
__global__ void prep_kernel(const float* __restrict__ W_in, const float* __restrict__ W_g1,
                            const float* __restrict__ W_g2, const float* __restrict__ W_m1,
                            const float* __restrict__ W_m2, const float* __restrict__ W_out,
                            const float* __restrict__ W_attn, unsigned short* __restrict__ wt)
{
    int i = blockIdx.x * 256 + threadIdx.x;
    unsigned short* WT_in = wt;                 // [128][96]
    unsigned short* WT_g1 = WT_in + 12288;      // [128][128]
    unsigned short* WT_g2 = WT_g1 + 16384;      // [128][128]
    unsigned short* WT_m1 = WT_g2 + 16384;      // [128][416]
    unsigned short* WT_m2 = WT_m1 + 53248;      // [128][128]
    unsigned short* WT_h  = WT_m2 + 16384;      // [32][128]
    if (i < 12288) { int n = i / 96, k = i - n * 96;
        WT_in[i] = (k < 86) ? f2bf(W_in[k * 128 + n]) : 0; return; }
    i -= 12288;
    if (i < 16384) { int n = i >> 7, k = i & 127;
        WT_g1[i] = f2bf(W_g1[k * 128 + n]); return; }
    i -= 16384;
    if (i < 16384) { int n = i >> 7, k = i & 127;
        WT_g2[i] = f2bf(W_g2[k * 128 + n]); return; }
    i -= 16384;
    if (i < 53248) { int n = i / 416, k = i - n * 416;
        WT_m1[i] = (k < 397) ? f2bf(W_m1[k * 128 + n]) : 0; return; }
    i -= 53248;
    if (i < 16384) { int n = i >> 7, k = i & 127;
        WT_m2[i] = f2bf(W_m2[k * 128 + n]); return; }
    i -= 16384;
    if (i < 4096) { int n = i >> 7, k = i & 127;
        WT_h[i] = (n < 13) ? f2bf(W_out[k * 13 + n])
                           : (n < 26 ? f2bf(W_attn[k * 13 + (n - 13)]) : 0); }
}

// ---------------------------------------------------------------------------
// root encoder (fp32, tiny)
// ---------------------------------------------------------------------------
__global__ void root_kernel(const float* __restrict__ root_repr,
                            const float* __restrict__ W_root,
                            const float* __restrict__ b_root,
                            float* __restrict__ root_emb)
{
    __shared__ float x[86];
    const int r = blockIdx.x, tid = threadIdx.x;  // 128
    if (tid < 86) x[tid] = root_repr[(size_t)r * 86 + tid];
    __syncthreads();
    float acc = b_root[tid];
    for (int k = 0; k < 86; ++k)
        acc = fmaf(x[k], W_root[k * 128 + tid], acc);
    root_emb[(size_t)r * 128 + tid] = fmaxf(acc, 0.0f);
}

// ---------------------------------------------------------------------------
// node pipeline: 1 block = strip of 64 nodes; 8 waves, each a 32x32 out-tile.
// LDS 35.3 KB -> 4 blocks/CU x 8 waves = 32 waves/CU (was 16): latency hiding.
// Segment reduction: 4x 16-row quarters, prefetch-then-scan; interior runs =
// plain stores, boundary runs = atomics.
// ---------------------------------------------------------------------------
__global__ __launch_bounds__(512, 8)
void node_kernel(const float* __restrict__ node_h, const int* __restrict__ seg_ids,
                 const unsigned short* __restrict__ WT_in, const float* __restrict__ b_in,
                 const unsigned short* __restrict__ WT_g1, const float* __restrict__ b_g1,
                 const unsigned short* __restrict__ WT_g2, const float* __restrict__ b_g2,
                 float* __restrict__ frag_sum, float* __restrict__ frag_cnt)
{
    __shared__ __align__(16) unsigned short X[64 * AST];
    __shared__ __align__(16) unsigned short Y[64 * AST];
    __shared__ int segs[64];
    const int tid = threadIdx.x, wv = tid >> 6, lane = tid & 63;
    const int mt0 = (wv >> 2) * 2, nt0 = (wv & 3) * 2;
    const long n0 = (long)blockIdx.x * 64;

    if (tid < 64) segs[tid] = seg_ids[n0 + tid];
    // stage x: 64 rows x 86 fp32 (contiguous 1376 float4) -> bf16 LDS
    {
        const float4* src = (const float4*)(node_h + n0 * 86);
#pragma unroll
        for (int j = 0; j < 3; ++j) {
            int i4 = j * 512 + tid;
            if (i4 < 1376) {
                float4 v = src[i4];
                int e = i4 << 2;
                int n = e / 86, k = e - n * 86;
                X[n * AST + k] = f2bf(v.x);
                int e1 = e + 1; n = e1 / 86; k = e1 - n * 86; X[n * AST + k] = f2bf(v.y);
                int e2 = e + 2; n = e2 / 86; k = e2 - n * 86; X[n * AST + k] = f2bf(v.z);
                int e3 = e + 3; n = e3 / 86; k = e3 - n * 86; X[n * AST + k] = f2bf(v.w);
            }
        }
        for (int idx = tid; idx < 640; idx += 512) {
            int n = idx / 10, k = idx - n * 10;
            X[n * AST + 86 + k] = 0;
        }
    }
    __syncthreads();

    float4v acc[2][2];
    layer22<96>(X, AST, WT_in, b_in, lane, mt0, nt0, acc);
    store22(acc, Y, lane, mt0, nt0, false);    // layer 1: NO relu
    __syncthreads();
    layer22<128>(Y, AST, WT_g1, b_g1, lane, mt0, nt0, acc);
    store22(acc, X, lane, mt0, nt0, true);
    __syncthreads();
    layer22<128>(X, AST, WT_g2, b_g2, lane, mt0, nt0, acc);
    store22(acc, Y, lane, mt0, nt0, true);     // h3 in Y
    __syncthreads();

    // reduction: thread (col = tid&127, quarter = tid>>7) scans 16 rows.
    // Prefetch all 16 LDS values first (no dependent ds_read chain).
    {
        const int col = tid & 127, qt = tid >> 7, r0 = qt << 4;
        float v[16];
#pragma unroll
        for (int i = 0; i < 16; ++i)
            v[i] = bf2f((unsigned)Y[(r0 + i) * AST + col]);
        const int prevSeg = (qt > 0) ? segs[r0 - 1] : -1;
        const int nextSeg = (qt < 3) ? segs[r0 + 16] : -1;
        int cur = segs[r0], runStart = r0;
        float sum = 0.f, cnt = 0.f;
#pragma unroll
        for (int i = 0; i < 16; ++i) {
            const int n = r0 + i;
            int s = segs[n];
            if (s != cur) {
                bool bnd = (runStart == r0) && (qt == 0 || prevSeg == cur);
                if (bnd) atomicAdd(&frag_sum[(size_t)cur * 128 + col], sum);
                else     frag_sum[(size_t)cur * 128 + col] = sum;
                if (col == 0) {
                    if (bnd) atomicAdd(&frag_cnt[cur], cnt);
                    else     frag_cnt[cur] = cnt;
                }
                sum = 0.f; cnt = 0.f; cur = s; runStart = n;
            }
            sum += v[i];
            cnt += 1.f;
        }
        bool bnd = ((runStart == r0) && (qt == 0 || prevSeg == cur))
                   || (qt == 3) || (nextSeg == cur);
        if (bnd) atomicAdd(&frag_sum[(size_t)cur * 128 + col], sum);
        else     frag_sum[(size_t)cur * 128 + col] = sum;
        if (col == 0) {
            if (bnd) atomicAdd(&frag_cnt[cur], cnt);
            else     frag_cnt[cur] = cnt;
        }
    }
}

// ---------------------------------------------------------------------------
// fragment MLP + heads: 1 block = 64 frags; cat staged in LDS, 8 waves
// (2 blocks/CU x 8 = 16 waves/CU, was 8).
// ---------------------------------------------------------------------------
__global__ __launch_bounds__(512, 4)
void frag_kernel(const float* __restrict__ root_emb, const float* __restrict__ frag_sum,
                 const float* __restrict__ frag_cnt, const int* __restrict__ ind_maps,
                 const int* __restrict__ broken,
                 const unsigned short* __restrict__ WT_m1, const float* __restrict__ b_m1,
                 const unsigned short* __restrict__ WT_m2, const float* __restrict__ b_m2,
                 const unsigned short* __restrict__ WT_h,
                 const float* __restrict__ b_out, const float* __restrict__ b_attn,
                 float* __restrict__ out0, float* __restrict__ out1)
{
    __shared__ __align__(16) unsigned short cat[64 * CST];   // 54,272 B
    __shared__ __align__(16) unsigned short Y[64 * AST];     // 17,408 B
    unsigned short* X2 = cat;                                // h2 reuses cat
    const int tid = threadIdx.x, wv = tid >> 6, lane = tid & 63;
    const int mt0 = (wv >> 2) * 2, nt0 = (wv & 3) * 2;
    const int col0 = lane & 15, q = lane >> 4;
    const long f0 = (long)blockIdx.x * 64;

    // build cat: row m = tid>>3, thread j = tid&7 covers k in [16j, 16j+16)
    {
        const int m = tid >> 3, j = tid & 7;
        int fc = (int)f0 + m; if (fc > 99999) fc = 99999;
        const int rid = ind_maps[fc];
        const float inv = 1.0f / fmaxf(frag_cnt[fc], 1.0f);
        unsigned short* row = cat + m * CST;
#pragma unroll
        for (int jj = 0; jj < 4; ++jj) {
            int k = j * 16 + jj * 4;
            float4 e = *(const float4*)(root_emb + (size_t)rid * 128 + k);
            float4 s = *(const float4*)(frag_sum + (size_t)fc * 128 + k);
            float sx = s.x * inv, sy = s.y * inv, sz = s.z * inv, sw = s.w * inv;
            row[k]     = f2bf(e.x); row[k + 1] = f2bf(e.y);
            row[k + 2] = f2bf(e.z); row[k + 3] = f2bf(e.w);
            row[128 + k]     = f2bf(e.x - sx); row[128 + k + 1] = f2bf(e.y - sy);
            row[128 + k + 2] = f2bf(e.z - sz); row[128 + k + 3] = f2bf(e.w - sw);
            row[256 + k]     = f2bf(sx); row[256 + k + 1] = f2bf(sy);
            row[256 + k + 2] = f2bf(sz); row[256 + k + 3] = f2bf(sw);
        }
        if (j == 7) {
            int b = broken[fc]; b = b < 0 ? 0 : (b > 12 ? 12 : b);
            for (int kk = 0; kk < 32; ++kk)
                row[384 + kk] = (kk == b) ? 0x3f80 : 0;   // bf16 1.0
        }
    }
    __syncthreads();

    float4v acc[2][2];
    layer22<416>(cat, CST, WT_m1, b_m1, lane, mt0, nt0, acc);
    store22(acc, Y, lane, mt0, nt0, true);     // h1
    __syncthreads();
    layer22<128>(Y, AST, WT_m2, b_m2, lane, mt0, nt0, acc);
    store22(acc, X2, lane, mt0, nt0, true);    // h2 (overwrites cat area)
    __syncthreads();

    // heads: wave wv: m-tile = wv&3, n-tile t = wv>>2 (26 valid cols), K=128
    {
        const int mrow = wv & 3, t = wv >> 2;
        const int cc = t * 16 + col0;
        float b = cc < 13 ? b_out[cc] : (cc < 26 ? b_attn[cc - 13] : 0.0f);
        float4v hacc = (float4v){b, b, b, b};
#pragma unroll
        for (int ks = 0; ks < 128; ks += 32) {
            const int k0 = ks + q * 8;
            short8 A = *(const short8*)(X2 + (mrow * 16 + col0) * AST + k0);
            short8 B = *(const short8*)(WT_h + (t * 16 + col0) * 128 + k0);
            hacc = __builtin_amdgcn_mfma_f32_16x16x32_bf16(A, B, hacc, 0, 0, 0);
        }
#pragma unroll
        for (int r = 0; r < 4; ++r) {
            long ff = f0 + mrow * 16 + q * 4 + r;
            if (ff < 100000) {
                float v = hacc[r];
                if (cc < 13)      out0[ff * 13 + cc] = 1.0f / (1.0f + expf(-v));
                else if (cc < 26) out1[ff * 13 + cc - 13] = v;
            }
        }
    }
}

extern "C" void kernel_launch(void* const* d_in, const int* in_sizes, int n_in,
                              void* d_out, int out_size, void* d_ws, size_t ws_size,
                              hipStream_t stream)
{
    const float* node_h    = (const float*)d_in[0];
    const int*   seg_ids   = (const int*)d_in[1];
    const float* root_repr = (const float*)d_in[2];
    const int*   ind_maps  = (const int*)d_in[3];
    const int*   broken    = (const int*)d_in[4];
    const float* W_root = (const float*)d_in[5];  const float* b_root = (const float*)d_in[6];
    const float* W_in   = (const float*)d_in[7];  const float* b_in   = (const float*)d_in[8];
    const float* W_g1   = (const float*)d_in[9];  const float* b_g1   = (const float*)d_in[10];
    const float* W_g2   = (const float*)d_in[11]; const float* b_g2   = (const float*)d_in[12];
    const float* W_m1   = (const float*)d_in[13]; const float* b_m1   = (const float*)d_in[14];
    const float* W_m2   = (const float*)d_in[15]; const float* b_m2   = (const float*)d_in[16];
    const float* W_out  = (const float*)d_in[17]; const float* b_out  = (const float*)d_in[18];
    const float* W_attn = (const float*)d_in[19]; const float* b_attn = (const float*)d_in[20];

    char* ws = (char*)d_ws;
    float* root_emb = (float*)ws;                          // 2000*128*4
    float* frag_sum = (float*)(ws + 1024000);              // 100000*128*4
    float* frag_cnt = (float*)(ws + 52224000);             // 100000*4
    unsigned short* wt = (unsigned short*)(ws + 52624000); // bf16 weights
    const unsigned short* WT_in = wt;
    const unsigned short* WT_g1 = wt + 12288;
    const unsigned short* WT_g2 = WT_g1 + 16384;
    const unsigned short* WT_m1 = WT_g2 + 16384;
    const unsigned short* WT_m2 = WT_m1 + 53248;
    const unsigned short* WT_h  = WT_m2 + 16384;

    hipMemsetAsync(frag_sum, 0, 51600000, stream);  // frag_sum + frag_cnt

    float* out0 = (float*)d_out;
    float* out1 = out0 + (size_t)100000 * 13;

    prep_kernel<<<464, 256, 0, stream>>>(W_in, W_g1, W_g2, W_m1, W_m2, W_out, W_attn, wt);
    root_kernel<<<2000, 128, 0, stream>>>(root_repr, W_root, b_root, root_emb);
    node_kernel<<<12500, 512, 0, stream>>>(node_h, seg_ids, WT_in, b_in,
                                           WT_g1, b_g1, WT_g2, b_g2, frag_sum, frag_cnt);
    frag_kernel<<<1563, 512, 0, stream>>>(root_emb, frag_sum, frag_cnt, ind_maps, broken,
                                          WT_m1, b_m1, WT_m2, b_m2, WT_h, b_out, b_attn,
                                          out0, out1);
}